// Round 12
// baseline (1288.680 us; speedup 1.0000x reference)
//
#include <hip/hip_runtime.h>
#include <cstddef>

// ---------------------------------------------------------------------------
// ChebNet MFMA bf16: B=32, N=1024, layers 6->128->512->1024 (K=3), maxpool,
// FC 1024->512->128->40. BC=16 x 2 chunks (~160 MB ws) when ws allows, else 8x4.
// Per layer: prep2 -> adj -> disscale(dis; X0t*=d in place) -> lx1 -> lx2 -> proj.
// A stays RAW bf16 (D folded into lx epilogues, round-3 algebra).
// lx: LDS dbuf K-loop (128f x 64n). proj: direct-global register fragments,
// NO LDS, NO barriers in K-loop (ping-pong reg sets).
// 1D grids, XCD-aware decode (sample = L & (BC-1)).
// ---------------------------------------------------------------------------

#define NN 1024

typedef unsigned short ushort_t;
typedef __bf16 bf16x8 __attribute__((ext_vector_type(8)));
typedef float f32x4 __attribute__((ext_vector_type(4)));

__device__ inline ushort_t f2bf(float f) {
    unsigned int u = __float_as_uint(f);
    u = (u + 0x7fffu + ((u >> 16) & 1u)) >> 16;
    return (ushort_t)u;
}
__device__ inline float bf2f(ushort_t s) {
    return __uint_as_float(((unsigned int)s) << 16);
}

__global__ void zero_kernel(float* __restrict__ p, int n) {
    int i = blockIdx.x * blockDim.x + threadIdx.x;
    if (i < n) p[i] = 0.f;
}

// W[p][Fi][Fo] fp32 -> Wt[p][Fo][Ks] bf16, LDS-tiled transpose, zero-pad K.
__global__ __launch_bounds__(256) void wconvT_kernel(
    const float* __restrict__ W, ushort_t* __restrict__ Wt, int Fi, int Fo, int Ks) {
    int p = blockIdx.z;
    int k0 = blockIdx.y * 64, g0 = blockIdx.x * 64;
    __shared__ float T[64][65];
    int t = threadIdx.x;
#pragma unroll
    for (int q = 0; q < 16; ++q) {
        int kr = (t >> 6) + 4 * q, gc = t & 63;
        int k = k0 + kr, g = g0 + gc;
        T[kr][gc] = (k < Fi && g < Fo) ? W[((size_t)p * Fi + k) * Fo + g] : 0.f;
    }
    __syncthreads();
#pragma unroll
    for (int q = 0; q < 16; ++q) {
        int gr = (t >> 6) + 4 * q, kc = t & 63;
        int g = g0 + gr, k = k0 + kc;
        if (g < Fo && k < Ks)
            Wt[((size_t)p * Fo + g) * Ks + k] = f2bf(T[kc][gr]);
    }
}

// Fused: hi/lo bf16 split (row-major, pad to Fp), transpose Xt, sq.
// 1D grid 16*BC: b = L & (BC-1), n0 = (L>>bsh)*64.
__global__ __launch_bounds__(256) void prep2_kernel(
    const float* __restrict__ X, ushort_t* __restrict__ hi, ushort_t* __restrict__ lo,
    ushort_t* __restrict__ Xt, float* __restrict__ sq, int F, int Fp, int bsh) {
    int L = blockIdx.x;
    int b = L & ((1 << bsh) - 1), n0 = (L >> bsh) * 64;
    int t = threadIdx.x;
    __shared__ float T[64][65];
    __shared__ float red[4][64];
    const float* Xb = X + ((size_t)b * NN + n0) * F;
    float sacc = 0.f;

    for (int f0 = 0; f0 < Fp; f0 += 64) {
        __syncthreads();
#pragma unroll
        for (int p = 0; p < 16; ++p) {
            int nr = (t >> 6) + 4 * p, fc = t & 63;
            int f = f0 + fc;
            T[nr][fc] = (f < F) ? Xb[(size_t)nr * F + f] : 0.f;
        }
        __syncthreads();
#pragma unroll
        for (int p = 0; p < 16; ++p) {
            int nr = (t >> 6) + 4 * p, fc = t & 63;
            int f = f0 + fc;
            if (f < Fp) {
                float x = T[nr][fc];
                ushort_t h = f2bf(x);
                size_t off = ((size_t)b * NN + n0 + nr) * Fp + f;
                hi[off] = h;
                lo[off] = f2bf(x - bf2f(h));
            }
        }
#pragma unroll
        for (int p = 0; p < 16; ++p) {
            int fr = (t >> 6) + 4 * p;
            int f = f0 + fr;
            if (f < F)
                Xt[((size_t)b * Fp + f) * NN + n0 + (t & 63)] = f2bf(T[t & 63][fr]);
        }
        {
            int nl = t & 63, fq = t >> 6;
#pragma unroll
            for (int fc = 0; fc < 16; ++fc) {
                float v = T[nl][fq * 16 + fc];
                sacc += v * v;
            }
        }
    }
    red[t >> 6][t & 63] = sacc;
    __syncthreads();
    if (t < 64)
        sq[(size_t)b * NN + n0 + t] = red[0][t] + red[1][t] + red[2][t] + red[3][t];
}

// A[b,n,m] = exp(2 x_n.x_m - sq_n - sq_m) -> bf16 (split hi/lo MFMA), dbuf;
// degree partials deg_part[slot][b][n], slot = m_tile*2+(wave&1).
// 1D grid 64*BC: b = L&(BC-1); rest = L>>bsh; m_tile = rest&7; n_tile = rest>>3.
__global__ __launch_bounds__(256) void adj_kernel(
    const ushort_t* __restrict__ hi, const ushort_t* __restrict__ lo,
    const float* __restrict__ sq, ushort_t* __restrict__ Abf,
    float* __restrict__ deg_part, int Fp, int bsh, int BCv) {
    int t = threadIdx.x;
    int L = blockIdx.x;
    int b = L & ((1 << bsh) - 1);
    int rest = L >> bsh;
    int m0 = (rest & 7) * 128, n0 = (rest >> 3) * 128;
    const ushort_t* Hb = hi + (size_t)b * NN * Fp;
    const ushort_t* Lb = lo + (size_t)b * NN * Fp;
    ushort_t* Ab = Abf + (size_t)b * NN * NN;
    const float* sqb = sq + (size_t)b * NN;

    int lane = t & 63, quad = lane >> 4, l16 = lane & 15, wave = t >> 6;
    int rowoff = (wave >> 1) * 64, coloff = (wave & 1) * 64;

    __shared__ __align__(16) ushort_t smem[40960];

    f32x4 acc[4][4];
#pragma unroll
    for (int i = 0; i < 4; ++i)
#pragma unroll
        for (int j = 0; j < 4; ++j) acc[i][j] = (f32x4){0.f, 0.f, 0.f, 0.f};

    int rr0 = t >> 2, kq = (t & 3) * 8;
    int rr1 = rr0 + 64;
    const ushort_t* pAh0 = Hb + (size_t)(n0 + rr0) * Fp + kq;
    const ushort_t* pAh1 = Hb + (size_t)(n0 + rr1) * Fp + kq;
    const ushort_t* pAl0 = Lb + (size_t)(n0 + rr0) * Fp + kq;
    const ushort_t* pAl1 = Lb + (size_t)(n0 + rr1) * Fp + kq;
    const ushort_t* pBh0 = Hb + (size_t)(m0 + rr0) * Fp + kq;
    const ushort_t* pBh1 = Hb + (size_t)(m0 + rr1) * Fp + kq;
    const ushort_t* pBl0 = Lb + (size_t)(m0 + rr0) * Fp + kq;
    const ushort_t* pBl1 = Lb + (size_t)(m0 + rr1) * Fp + kq;
    int o0 = rr0 * 40 + kq, o1 = rr1 * 40 + kq;

    {
        *(uint4*)&smem[o0]         = *(const uint4*)pAh0;
        *(uint4*)&smem[o1]         = *(const uint4*)pAh1;
        *(uint4*)&smem[5120 + o0]  = *(const uint4*)pAl0;
        *(uint4*)&smem[5120 + o1]  = *(const uint4*)pAl1;
        *(uint4*)&smem[10240 + o0] = *(const uint4*)pBh0;
        *(uint4*)&smem[10240 + o1] = *(const uint4*)pBh1;
        *(uint4*)&smem[15360 + o0] = *(const uint4*)pBl0;
        *(uint4*)&smem[15360 + o1] = *(const uint4*)pBl1;
    }
    __syncthreads();

    int NIT = Fp >> 5;
    for (int it = 0; it < NIT; ++it) {
        int cur = (it & 1) * 20480;
        int nxt = 20480 - cur;
        uint4 rh0, rh1, rl0, rl1, sh0, sh1, sl0, sl1;
        if (it + 1 < NIT) {
            int k = (it + 1) * 32;
            rh0 = *(const uint4*)(pAh0 + k); rh1 = *(const uint4*)(pAh1 + k);
            rl0 = *(const uint4*)(pAl0 + k); rl1 = *(const uint4*)(pAl1 + k);
            sh0 = *(const uint4*)(pBh0 + k); sh1 = *(const uint4*)(pBh1 + k);
            sl0 = *(const uint4*)(pBl0 + k); sl1 = *(const uint4*)(pBl1 + k);
        }
        ushort_t* Ah = smem + cur;
        ushort_t* Al = smem + cur + 5120;
        ushort_t* Bh = smem + cur + 10240;
        ushort_t* Bl = smem + cur + 15360;
        bf16x8 ah[4], al[4], bh[4], bl[4];
#pragma unroll
        for (int i = 0; i < 4; ++i) {
            ah[i] = *(const bf16x8*)&Ah[(rowoff + i * 16 + l16) * 40 + quad * 8];
            al[i] = *(const bf16x8*)&Al[(rowoff + i * 16 + l16) * 40 + quad * 8];
        }
#pragma unroll
        for (int j = 0; j < 4; ++j) {
            bh[j] = *(const bf16x8*)&Bh[(coloff + j * 16 + l16) * 40 + quad * 8];
            bl[j] = *(const bf16x8*)&Bl[(coloff + j * 16 + l16) * 40 + quad * 8];
        }
#pragma unroll
        for (int i = 0; i < 4; ++i)
#pragma unroll
            for (int j = 0; j < 4; ++j) {
                acc[i][j] = __builtin_amdgcn_mfma_f32_16x16x32_bf16(al[i], bh[j], acc[i][j], 0, 0, 0);
                acc[i][j] = __builtin_amdgcn_mfma_f32_16x16x32_bf16(ah[i], bl[j], acc[i][j], 0, 0, 0);
                acc[i][j] = __builtin_amdgcn_mfma_f32_16x16x32_bf16(ah[i], bh[j], acc[i][j], 0, 0, 0);
            }
        if (it + 1 < NIT) {
            *(uint4*)&smem[nxt + o0]         = rh0;
            *(uint4*)&smem[nxt + o1]         = rh1;
            *(uint4*)&smem[nxt + 5120 + o0]  = rl0;
            *(uint4*)&smem[nxt + 5120 + o1]  = rl1;
            *(uint4*)&smem[nxt + 10240 + o0] = sh0;
            *(uint4*)&smem[nxt + 10240 + o1] = sh1;
            *(uint4*)&smem[nxt + 15360 + o0] = sl0;
            *(uint4*)&smem[nxt + 15360 + o1] = sl1;
        }
        __syncthreads();
    }

    float rs[4][4];
#pragma unroll
    for (int i = 0; i < 4; ++i)
#pragma unroll
        for (int r = 0; r < 4; ++r) rs[i][r] = 0.f;

#pragma unroll
    for (int j = 0; j < 4; ++j) {
        int m = m0 + coloff + j * 16 + l16;
        float sm = sqb[m];
#pragma unroll
        for (int i = 0; i < 4; ++i) {
#pragma unroll
            for (int r = 0; r < 4; ++r) {
                int n = n0 + rowoff + i * 16 + quad * 4 + r;
                float v = __expf(2.f * acc[i][j][r] - sqb[n] - sm);
                Ab[(size_t)n * NN + m] = f2bf(v);
                rs[i][r] += v;
            }
        }
    }
    int slot = (rest & 7) * 2 + (wave & 1);
#pragma unroll
    for (int i = 0; i < 4; ++i)
#pragma unroll
        for (int r = 0; r < 4; ++r) {
            float s = rs[i][r];
            s += __shfl_xor(s, 1);
            s += __shfl_xor(s, 2);
            s += __shfl_xor(s, 4);
            s += __shfl_xor(s, 8);
            if (l16 == 0)
                deg_part[((size_t)slot * BCv + b) * NN + n0 + rowoff + i * 16 + quad * 4 + r] = s;
        }
}

// dis[b][n] = rsqrt(sum of 16 deg partials); X0t[b][f][n0..] *= dis[n] in place.
// 1D grid 16*BC: b = L&(BC-1), n0 = (L>>bsh)*64.
__global__ __launch_bounds__(256) void disscale_kernel(
    ushort_t* __restrict__ Xt, const float* __restrict__ deg_part,
    float* __restrict__ dis, int Fp, int bsh, int BCv) {
    int L = blockIdx.x;
    int b = L & ((1 << bsh) - 1), n0 = (L >> bsh) * 64;
    int t = threadIdx.x;
    __shared__ float dloc[64];
    if (t < 64) {
        float s = 0.f;
#pragma unroll
        for (int k = 0; k < 16; ++k) s += deg_part[((size_t)k * BCv + b) * NN + n0 + t];
        float d = rsqrtf(s);
        dloc[t] = d;
        dis[(size_t)b * NN + n0 + t] = d;
    }
    __syncthreads();
    int lane = t & 63, fq = t >> 6;
    float d = dloc[lane];
    ushort_t* Xb = Xt + (size_t)b * Fp * NN + n0 + lane;
    for (int f = fq; f < Fp; f += 4) {
        size_t off = (size_t)f * NN;
        Xb[off] = f2bf(bf2f(Xb[off]) * d);
    }
}

// lx: acc[f][n] = sum_k in_t[f][k] * A[n][k]  (A raw symmetric), dbuf K-loop.
// in_t is node-scaled (S). Tile 128f x 64n, 4 waves, acc[2][4].
// mode0: out_t = S1 = xin - dn^2*acc; out_b = X1 = inv*xin - dn*acc.
// mode1: out_b = X2 = inv*(2*xin - x0) - 2*dn*acc.
// 1D grid ft*16*BC: b = L&(BC-1); rest = L>>bsh; f_tile = rest%ft; n_tile = rest/ft.
__global__ __launch_bounds__(256) void lx_kernel(
    const ushort_t* __restrict__ Abf, const float* __restrict__ dis,
    const ushort_t* __restrict__ in_t, const ushort_t* __restrict__ x0t,
    ushort_t* __restrict__ out_t, ushort_t* __restrict__ out_b,
    int F, int Fp, int mode, int ft, int bsh) {
    int t = threadIdx.x;
    int L = blockIdx.x;
    int b = L & ((1 << bsh) - 1);
    int rest = L >> bsh;
    int m0 = (rest % ft) * 128;   // f tile (128)
    int n0 = (rest / ft) * 64;    // n tile (64)
    const ushort_t* Ain = in_t + (size_t)b * Fp * NN;
    const ushort_t* Ab = Abf + (size_t)b * NN * NN;

    int lane = t & 63, quad = lane >> 4, l16 = lane & 15, wave = t >> 6;
    int rowoff = wave * 32;

    __shared__ __align__(16) ushort_t smem[15360];

    f32x4 acc[2][4];
#pragma unroll
    for (int i = 0; i < 2; ++i)
#pragma unroll
        for (int j = 0; j < 4; ++j) acc[i][j] = (f32x4){0.f, 0.f, 0.f, 0.f};

    int rr0 = t >> 2, kq = (t & 3) * 8;
    int rr1 = rr0 + 64;
    bool av0 = (m0 + rr0 < F), av1 = (m0 + rr1 < F);
    const ushort_t* pA0 = Ain + (size_t)(m0 + rr0) * NN + kq;
    const ushort_t* pA1 = Ain + (size_t)(m0 + rr1) * NN + kq;
    const ushort_t* pB0 = Ab + (size_t)(n0 + rr0) * NN + kq;
    int o0 = rr0 * 40 + kq, o1 = rr1 * 40 + kq;
    const uint4 z4 = make_uint4(0u, 0u, 0u, 0u);

    {
        *(uint4*)&smem[o0]        = av0 ? *(const uint4*)pA0 : z4;
        *(uint4*)&smem[o1]        = av1 ? *(const uint4*)pA1 : z4;
        *(uint4*)&smem[5120 + o0] = *(const uint4*)pB0;
    }
    __syncthreads();

    for (int it = 0; it < 32; ++it) {
        int cur = (it & 1) * 7680;
        int nxt = 7680 - cur;
        uint4 ra0, ra1, rb0;
        if (it < 31) {
            int k = (it + 1) * 32;
            ra0 = av0 ? *(const uint4*)(pA0 + k) : z4;
            ra1 = av1 ? *(const uint4*)(pA1 + k) : z4;
            rb0 = *(const uint4*)(pB0 + k);
        }
        ushort_t* AsP = smem + cur;
        ushort_t* BsP = AsP + 5120;
        bf16x8 af[2], bfv[4];
#pragma unroll
        for (int i = 0; i < 2; ++i)
            af[i] = *(const bf16x8*)&AsP[(rowoff + i * 16 + l16) * 40 + quad * 8];
#pragma unroll
        for (int j = 0; j < 4; ++j)
            bfv[j] = *(const bf16x8*)&BsP[(j * 16 + l16) * 40 + quad * 8];
#pragma unroll
        for (int i = 0; i < 2; ++i)
#pragma unroll
            for (int j = 0; j < 4; ++j)
                acc[i][j] = __builtin_amdgcn_mfma_f32_16x16x32_bf16(af[i], bfv[j], acc[i][j], 0, 0, 0);
        if (it < 31) {
            *(uint4*)&smem[nxt + o0]        = ra0;
            *(uint4*)&smem[nxt + o1]        = ra1;
            *(uint4*)&smem[nxt + 5120 + o0] = rb0;
        }
        __syncthreads();
    }

#pragma unroll
    for (int j = 0; j < 4; ++j) {
        int nl = j * 16 + l16;
        int n = n0 + nl;
        float dn = dis[(size_t)b * NN + n];
        float inv = 1.f / dn;
        float dn2 = dn * dn;
#pragma unroll
        for (int i = 0; i < 2; ++i) {
#pragma unroll
            for (int r = 0; r < 4; ++r) {
                int fl = rowoff + i * 16 + quad * 4 + r;
                int f = m0 + fl;
                float o = 0.f;
                if (f < F) {
                    float a = acc[i][j][r];
                    size_t off = (size_t)f * NN + n;
                    float xin = bf2f(Ain[off]);
                    if (mode == 0) {
                        out_t[(size_t)b * Fp * NN + off] = f2bf(xin - dn2 * a);
                        o = inv * xin - dn * a;
                    } else {
                        float x0 = bf2f(x0t[(size_t)b * Fp * NN + off]);
                        o = inv * (2.f * xin - x0) - 2.f * dn * a;
                    }
                }
                smem[nl * 128 + (((fl >> 3) ^ (nl & 7)) << 3) + (fl & 7)] = f2bf(o);
            }
        }
    }
    __syncthreads();
    for (int s2 = t; s2 < 1024; s2 += 256) {
        int nl = s2 >> 4, oct = s2 & 15;
        int fg = m0 + oct * 8;
        if (fg < Fp) {
            uint4 v = *(const uint4*)&smem[nl * 128 + ((oct ^ (nl & 7)) << 3)];
            *(uint4*)(out_b + ((size_t)b * NN + n0 + nl) * Fp + fg) = v;
        }
    }
}

// Out[r][g] = relu( sum_p Xp[r][:].Wt[p][g][:] + bias[g] ).
// Direct-global register fragments, NO LDS, no K-loop barriers; ping-pong sets.
// layer3: fused maxpool. 1D grid n_g*8*BC: c=L&(BC-1); rest=L>>bsh;
// g=rest%n_g; r_tile = c*8 + rest/n_g.
__global__ __launch_bounds__(256) void proj_kernel(
    const ushort_t* __restrict__ X0, const ushort_t* __restrict__ X1,
    const ushort_t* __restrict__ X2, const ushort_t* __restrict__ Wt,
    const float* __restrict__ bias, float* __restrict__ O, float* __restrict__ pool,
    int Fp, int Fo, int b0, int n_g, int bsh) {
    int t = threadIdx.x;
    int L = blockIdx.x;
    int c = L & ((1 << bsh) - 1);
    int rest = L >> bsh;
    int g0 = (rest % n_g) * 128;
    int r0 = (c * 8 + rest / n_g) * 128;
    int lane = t & 63, quad = lane >> 4, l16 = lane & 15, wave = t >> 6;
    int rowoff = (wave >> 1) * 64, coloff = (wave & 1) * 64;

    f32x4 acc[4][4];
#pragma unroll
    for (int i = 0; i < 4; ++i)
#pragma unroll
        for (int j = 0; j < 4; ++j) acc[i][j] = (f32x4){0.f, 0.f, 0.f, 0.f};

    const ushort_t* Xs[3] = {X0, X1, X2};
    int nk = Fp >> 5;
    size_t arow = (size_t)(r0 + rowoff + l16) * Fp + quad * 8;
    size_t brow0 = (size_t)(g0 + coloff + l16) * Fp + quad * 8;
    size_t rstep = (size_t)16 * Fp;

    bf16x8 fa0[4], fw0[4], fa1[4], fw1[4];
    for (int p = 0; p < 3; ++p) {
        const ushort_t* xb = Xs[p] + arow;
        const ushort_t* wb = Wt + (size_t)p * Fo * Fp + brow0;
#pragma unroll
        for (int i = 0; i < 4; ++i) fa0[i] = *(const bf16x8*)(xb + (size_t)i * rstep);
#pragma unroll
        for (int j = 0; j < 4; ++j) fw0[j] = *(const bf16x8*)(wb + (size_t)j * rstep);
        for (int ks = 0; ks < nk; ks += 2) {
            if (ks + 1 < nk) {
                int k = (ks + 1) * 32;
#pragma unroll
                for (int i = 0; i < 4; ++i) fa1[i] = *(const bf16x8*)(xb + (size_t)i * rstep + k);
#pragma unroll
                for (int j = 0; j < 4; ++j) fw1[j] = *(const bf16x8*)(wb + (size_t)j * rstep + k);
            }
#pragma unroll
            for (int i = 0; i < 4; ++i)
#pragma unroll
                for (int j = 0; j < 4; ++j)
                    acc[i][j] = __builtin_amdgcn_mfma_f32_16x16x32_bf16(fa0[i], fw0[j], acc[i][j], 0, 0, 0);
            if (ks + 2 < nk) {
                int k = (ks + 2) * 32;
#pragma unroll
                for (int i = 0; i < 4; ++i) fa0[i] = *(const bf16x8*)(xb + (size_t)i * rstep + k);
#pragma unroll
                for (int j = 0; j < 4; ++j) fw0[j] = *(const bf16x8*)(wb + (size_t)j * rstep + k);
            }
            if (ks + 1 < nk) {
#pragma unroll
                for (int i = 0; i < 4; ++i)
#pragma unroll
                    for (int j = 0; j < 4; ++j)
                        acc[i][j] = __builtin_amdgcn_mfma_f32_16x16x32_bf16(fa1[i], fw1[j], acc[i][j], 0, 0, 0);
            }
        }
    }

    float bias_l[4];
#pragma unroll
    for (int j = 0; j < 4; ++j) bias_l[j] = bias[g0 + coloff + j * 16 + l16];

    if (O) {
#pragma unroll
        for (int i = 0; i < 4; ++i) {
#pragma unroll
            for (int r = 0; r < 4; ++r) {
                int row = r0 + rowoff + i * 16 + quad * 4 + r;
#pragma unroll
                for (int j = 0; j < 4; ++j) {
                    int g = g0 + coloff + j * 16 + l16;
                    O[(size_t)row * Fo + g] = fmaxf(acc[i][j][r] + bias_l[j], 0.f);
                }
            }
        }
    } else {
        float mj[4];
#pragma unroll
        for (int j = 0; j < 4; ++j) {
            float m = 0.f;
#pragma unroll
            for (int i = 0; i < 4; ++i)
#pragma unroll
                for (int r = 0; r < 4; ++r)
                    m = fmaxf(m, acc[i][j][r] + bias_l[j]);
            m = fmaxf(m, 0.f);
            m = fmaxf(m, __shfl_xor(m, 16));
            m = fmaxf(m, __shfl_xor(m, 32));
            mj[j] = m;
        }
        if (quad == 0) {
            int smp = b0 + (r0 >> 10);
#pragma unroll
            for (int j = 0; j < 4; ++j)
                atomicMax((int*)&pool[(size_t)smp * 1024 + g0 + coloff + j * 16 + l16],
                          __float_as_int(mj[j]));
        }
    }
}

// fc: block = (row, 64-col tile); 4 K-slices x 64 cols; LDS reduce.
__global__ __launch_bounds__(256) void fc_kernel(
    const float* __restrict__ In, const float* __restrict__ W,
    const float* __restrict__ bias, float* __restrict__ out,
    int K, int Nout, int relu) {
    int r = blockIdx.y;
    int c0 = blockIdx.x * 64;
    int t = threadIdx.x;
    int cl = t & 63, ks = t >> 6;
    int c = c0 + cl;
    int kchunk = K >> 2;
    int k0 = ks * kchunk, k1 = k0 + kchunk;
    float s = 0.f;
    if (c < Nout) {
        const float* ip = In + (size_t)r * K;
        const float* wp = W + c;
#pragma unroll 4
        for (int k = k0; k < k1; ++k) s += ip[k] * wp[(size_t)k * Nout];
    }
    __shared__ float red[4][64];
    red[ks][cl] = s;
    __syncthreads();
    if (t < 64 && c0 + t < Nout) {
        float v = red[0][t] + red[1][t] + red[2][t] + red[3][t] + bias[c0 + t];
        if (relu) v = fmaxf(v, 0.f);
        out[(size_t)r * Nout + c0 + t] = v;
    }
}

// ---------------------------------------------------------------------------
extern "C" void kernel_launch(void* const* d_in, const int* in_sizes, int n_in,
                              void* d_out, int out_size, void* d_ws, size_t ws_size,
                              hipStream_t stream) {
    const float* x    = (const float*)d_in[0];
    const float* W1   = (const float*)d_in[1];
    const float* b1   = (const float*)d_in[2];
    const float* W2   = (const float*)d_in[3];
    const float* b2   = (const float*)d_in[4];
    const float* W3   = (const float*)d_in[5];
    const float* b3   = (const float*)d_in[6];
    const float* fc1w = (const float*)d_in[7];
    const float* fc1b = (const float*)d_in[8];
    const float* fc2w = (const float*)d_in[9];
    const float* fc2b = (const float*)d_in[10];
    const float* fc3w = (const float*)d_in[11];
    const float* fc3b = (const float*)d_in[12];
    float* out = (float*)d_out;

    auto need = [](size_t BCv) -> size_t {
        size_t us = (size_t)BCv * 1024;
        return 2 * (us * 1024) + 10 * (us * 512) + 2 * 1781760ull +
               4 * (us * 128) + 4 * (us * 512) + 4 * us + 64 * us + 4 * us +
               4 * (32768ull + 16384 + 4096) + 256;
    };
    int BCv = (ws_size >= need(16)) ? 16 : 8;
    int NCH = 32 / BCv;
    int bsh = (BCv == 16) ? 4 : 3;

    size_t usc = (size_t)BCv * 1024;
    size_t Asz = usc * 1024;           // ushorts
    size_t SLv = usc * 512;            // ushorts
    ushort_t* Abf  = (ushort_t*)d_ws;
    ushort_t* X0hi = Abf + Asz;
    ushort_t* X0lo = X0hi + SLv;       // aliases X2b (disjoint lifetime)
    ushort_t* X0t  = X0lo + SLv;
    ushort_t* X1t  = X0t + SLv;
    ushort_t* X1b  = X1t + SLv;
    ushort_t* Wt   = X1b + SLv;        // 1781760 ushorts
    float* O1   = (float*)(Wt + 1781760);
    float* O2   = O1 + usc * 128;
    float* sq   = O2 + usc * 512;
    float* degp = sq + usc;            // 16*BC*NN
    float* dis  = degp + 16 * usc;     // BC*NN
    float* pool = dis + usc;           // 32*1024
    float* f1   = pool + 32768;
    float* f2   = f1 + 16384;
    ushort_t* X2b = X0lo;              // alias

    wconvT_kernel<<<dim3(2, 1, 3), 256, 0, stream>>>(W1, Wt, 6, 128, 32);
    wconvT_kernel<<<dim3(8, 2, 3), 256, 0, stream>>>(W2, Wt + 12288, 128, 512, 128);
    wconvT_kernel<<<dim3(16, 8, 3), 256, 0, stream>>>(W3, Wt + 208896, 512, 1024, 512);
    zero_kernel<<<128, 256, 0, stream>>>(pool, 32768);

    for (int c = 0; c < NCH; ++c) {
        int b0 = c * BCv;
        struct LayerDef {
            const float* X; int F, Fp, Fo;
            const ushort_t* Wtl; const float* bias; float* O;
        };
        LayerDef L[3] = {
            { x + (size_t)b0 * NN * 6, 6,   32,  128,  Wt,          b1, O1 },
            { O1,                      128, 128, 512,  Wt + 12288,  b2, O2 },
            { O2,                      512, 512, 1024, Wt + 208896, b3, nullptr },
        };
        for (int li = 0; li < 3; ++li) {
            LayerDef& Ld = L[li];
            int F = Ld.F, Fp = Ld.Fp;
            int ft = (F + 127) / 128;
            int n_g = Ld.Fo / 128;
            prep2_kernel<<<16 * BCv, 256, 0, stream>>>(Ld.X, X0hi, X0lo, X0t, sq, F, Fp, bsh);
            adj_kernel<<<64 * BCv, 256, 0, stream>>>(X0hi, X0lo, sq, Abf, degp, Fp, bsh, BCv);
            disscale_kernel<<<16 * BCv, 256, 0, stream>>>(X0t, degp, dis, Fp, bsh, BCv);
            lx_kernel<<<ft * 16 * BCv, 256, 0, stream>>>(
                Abf, dis, X0t, nullptr, X1t, X1b, F, Fp, 0, ft, bsh);
            lx_kernel<<<ft * 16 * BCv, 256, 0, stream>>>(
                Abf, dis, X1t, X0t, nullptr, X2b, F, Fp, 1, ft, bsh);
            proj_kernel<<<n_g * 8 * BCv, 256, 0, stream>>>(
                X0hi, X1b, X2b, Ld.Wtl, Ld.bias, Ld.O, pool, Fp, Ld.Fo, b0, n_g, bsh);
        }
    }

    fc_kernel<<<dim3(8, 32), 256, 0, stream>>>(pool, fc1w, fc1b, f1, 1024, 512, 1);
    fc_kernel<<<dim3(2, 32), 256, 0, stream>>>(f1, fc2w, fc2b, f2, 512, 128, 1);
    fc_kernel<<<dim3(1, 32), 256, 0, stream>>>(f2, fc3w, fc3b, out, 128, 40, 0);
}

// Round 13
// 1056.942 us; speedup vs baseline: 1.2193x; 1.2193x over previous
//
#include <hip/hip_runtime.h>
#include <cstddef>

// ---------------------------------------------------------------------------
// ChebNet MFMA bf16: B=32, N=1024, layers 6->128->512->1024 (K=3), maxpool,
// FC 1024->512->128->40. BC=16 x 2 chunks (~160 MB ws) when ws allows, else 8x4.
// Per layer: prep2 -> adj -> disscale(dis; X0t*=d in place) -> lx1 -> lx2 -> proj.
// A stays RAW bf16 (D folded into lx epilogues). GEMMs: 2-stage LDS double
// buffer w/ single register prefetch (direct-global proj regressed: L1 too
// small for 64-row fragment working set -> latency-bound; reverted r12->r10).
// lx: 128f x 64n tiles. 1D grids, XCD-aware decode (sample = L & (BC-1)).
// ---------------------------------------------------------------------------

#define NN 1024

typedef unsigned short ushort_t;
typedef __bf16 bf16x8 __attribute__((ext_vector_type(8)));
typedef float f32x4 __attribute__((ext_vector_type(4)));

__device__ inline ushort_t f2bf(float f) {
    unsigned int u = __float_as_uint(f);
    u = (u + 0x7fffu + ((u >> 16) & 1u)) >> 16;
    return (ushort_t)u;
}
__device__ inline float bf2f(ushort_t s) {
    return __uint_as_float(((unsigned int)s) << 16);
}

__global__ void zero_kernel(float* __restrict__ p, int n) {
    int i = blockIdx.x * blockDim.x + threadIdx.x;
    if (i < n) p[i] = 0.f;
}

// W[p][Fi][Fo] fp32 -> Wt[p][Fo][Ks] bf16, LDS-tiled transpose, zero-pad K.
__global__ __launch_bounds__(256) void wconvT_kernel(
    const float* __restrict__ W, ushort_t* __restrict__ Wt, int Fi, int Fo, int Ks) {
    int p = blockIdx.z;
    int k0 = blockIdx.y * 64, g0 = blockIdx.x * 64;
    __shared__ float T[64][65];
    int t = threadIdx.x;
#pragma unroll
    for (int q = 0; q < 16; ++q) {
        int kr = (t >> 6) + 4 * q, gc = t & 63;
        int k = k0 + kr, g = g0 + gc;
        T[kr][gc] = (k < Fi && g < Fo) ? W[((size_t)p * Fi + k) * Fo + g] : 0.f;
    }
    __syncthreads();
#pragma unroll
    for (int q = 0; q < 16; ++q) {
        int gr = (t >> 6) + 4 * q, kc = t & 63;
        int g = g0 + gr, k = k0 + kc;
        if (g < Fo && k < Ks)
            Wt[((size_t)p * Fo + g) * Ks + k] = f2bf(T[kc][gr]);
    }
}

// Fused: hi/lo bf16 split (row-major, pad to Fp), transpose Xt, sq.
// 1D grid 16*BC: b = L & (BC-1), n0 = (L>>bsh)*64.
__global__ __launch_bounds__(256) void prep2_kernel(
    const float* __restrict__ X, ushort_t* __restrict__ hi, ushort_t* __restrict__ lo,
    ushort_t* __restrict__ Xt, float* __restrict__ sq, int F, int Fp, int bsh) {
    int L = blockIdx.x;
    int b = L & ((1 << bsh) - 1), n0 = (L >> bsh) * 64;
    int t = threadIdx.x;
    __shared__ float T[64][65];
    __shared__ float red[4][64];
    const float* Xb = X + ((size_t)b * NN + n0) * F;
    float sacc = 0.f;

    for (int f0 = 0; f0 < Fp; f0 += 64) {
        __syncthreads();
#pragma unroll
        for (int p = 0; p < 16; ++p) {
            int nr = (t >> 6) + 4 * p, fc = t & 63;
            int f = f0 + fc;
            T[nr][fc] = (f < F) ? Xb[(size_t)nr * F + f] : 0.f;
        }
        __syncthreads();
#pragma unroll
        for (int p = 0; p < 16; ++p) {
            int nr = (t >> 6) + 4 * p, fc = t & 63;
            int f = f0 + fc;
            if (f < Fp) {
                float x = T[nr][fc];
                ushort_t h = f2bf(x);
                size_t off = ((size_t)b * NN + n0 + nr) * Fp + f;
                hi[off] = h;
                lo[off] = f2bf(x - bf2f(h));
            }
        }
#pragma unroll
        for (int p = 0; p < 16; ++p) {
            int fr = (t >> 6) + 4 * p;
            int f = f0 + fr;
            if (f < F)
                Xt[((size_t)b * Fp + f) * NN + n0 + (t & 63)] = f2bf(T[t & 63][fr]);
        }
        {
            int nl = t & 63, fq = t >> 6;
#pragma unroll
            for (int fc = 0; fc < 16; ++fc) {
                float v = T[nl][fq * 16 + fc];
                sacc += v * v;
            }
        }
    }
    red[t >> 6][t & 63] = sacc;
    __syncthreads();
    if (t < 64)
        sq[(size_t)b * NN + n0 + t] = red[0][t] + red[1][t] + red[2][t] + red[3][t];
}

// A[b,n,m] = exp(2 x_n.x_m - sq_n - sq_m) -> bf16 (split hi/lo MFMA), dbuf;
// degree partials deg_part[slot][b][n], slot = m_tile*2+(wave&1).
// 1D grid 64*BC: b = L&(BC-1); rest = L>>bsh; m_tile = rest&7; n_tile = rest>>3.
__global__ __launch_bounds__(256) void adj_kernel(
    const ushort_t* __restrict__ hi, const ushort_t* __restrict__ lo,
    const float* __restrict__ sq, ushort_t* __restrict__ Abf,
    float* __restrict__ deg_part, int Fp, int bsh, int BCv) {
    int t = threadIdx.x;
    int L = blockIdx.x;
    int b = L & ((1 << bsh) - 1);
    int rest = L >> bsh;
    int m0 = (rest & 7) * 128, n0 = (rest >> 3) * 128;
    const ushort_t* Hb = hi + (size_t)b * NN * Fp;
    const ushort_t* Lb = lo + (size_t)b * NN * Fp;
    ushort_t* Ab = Abf + (size_t)b * NN * NN;
    const float* sqb = sq + (size_t)b * NN;

    int lane = t & 63, quad = lane >> 4, l16 = lane & 15, wave = t >> 6;
    int rowoff = (wave >> 1) * 64, coloff = (wave & 1) * 64;

    __shared__ __align__(16) ushort_t smem[40960];

    f32x4 acc[4][4];
#pragma unroll
    for (int i = 0; i < 4; ++i)
#pragma unroll
        for (int j = 0; j < 4; ++j) acc[i][j] = (f32x4){0.f, 0.f, 0.f, 0.f};

    int rr0 = t >> 2, kq = (t & 3) * 8;
    int rr1 = rr0 + 64;
    const ushort_t* pAh0 = Hb + (size_t)(n0 + rr0) * Fp + kq;
    const ushort_t* pAh1 = Hb + (size_t)(n0 + rr1) * Fp + kq;
    const ushort_t* pAl0 = Lb + (size_t)(n0 + rr0) * Fp + kq;
    const ushort_t* pAl1 = Lb + (size_t)(n0 + rr1) * Fp + kq;
    const ushort_t* pBh0 = Hb + (size_t)(m0 + rr0) * Fp + kq;
    const ushort_t* pBh1 = Hb + (size_t)(m0 + rr1) * Fp + kq;
    const ushort_t* pBl0 = Lb + (size_t)(m0 + rr0) * Fp + kq;
    const ushort_t* pBl1 = Lb + (size_t)(m0 + rr1) * Fp + kq;
    int o0 = rr0 * 40 + kq, o1 = rr1 * 40 + kq;

    {
        *(uint4*)&smem[o0]         = *(const uint4*)pAh0;
        *(uint4*)&smem[o1]         = *(const uint4*)pAh1;
        *(uint4*)&smem[5120 + o0]  = *(const uint4*)pAl0;
        *(uint4*)&smem[5120 + o1]  = *(const uint4*)pAl1;
        *(uint4*)&smem[10240 + o0] = *(const uint4*)pBh0;
        *(uint4*)&smem[10240 + o1] = *(const uint4*)pBh1;
        *(uint4*)&smem[15360 + o0] = *(const uint4*)pBl0;
        *(uint4*)&smem[15360 + o1] = *(const uint4*)pBl1;
    }
    __syncthreads();

    int NIT = Fp >> 5;
    for (int it = 0; it < NIT; ++it) {
        int cur = (it & 1) * 20480;
        int nxt = 20480 - cur;
        uint4 rh0, rh1, rl0, rl1, sh0, sh1, sl0, sl1;
        if (it + 1 < NIT) {
            int k = (it + 1) * 32;
            rh0 = *(const uint4*)(pAh0 + k); rh1 = *(const uint4*)(pAh1 + k);
            rl0 = *(const uint4*)(pAl0 + k); rl1 = *(const uint4*)(pAl1 + k);
            sh0 = *(const uint4*)(pBh0 + k); sh1 = *(const uint4*)(pBh1 + k);
            sl0 = *(const uint4*)(pBl0 + k); sl1 = *(const uint4*)(pBl1 + k);
        }
        ushort_t* Ah = smem + cur;
        ushort_t* Al = smem + cur + 5120;
        ushort_t* Bh = smem + cur + 10240;
        ushort_t* Bl = smem + cur + 15360;
        bf16x8 ah[4], al[4], bh[4], bl[4];
#pragma unroll
        for (int i = 0; i < 4; ++i) {
            ah[i] = *(const bf16x8*)&Ah[(rowoff + i * 16 + l16) * 40 + quad * 8];
            al[i] = *(const bf16x8*)&Al[(rowoff + i * 16 + l16) * 40 + quad * 8];
        }
#pragma unroll
        for (int j = 0; j < 4; ++j) {
            bh[j] = *(const bf16x8*)&Bh[(coloff + j * 16 + l16) * 40 + quad * 8];
            bl[j] = *(const bf16x8*)&Bl[(coloff + j * 16 + l16) * 40 + quad * 8];
        }
#pragma unroll
        for (int i = 0; i < 4; ++i)
#pragma unroll
            for (int j = 0; j < 4; ++j) {
                acc[i][j] = __builtin_amdgcn_mfma_f32_16x16x32_bf16(al[i], bh[j], acc[i][j], 0, 0, 0);
                acc[i][j] = __builtin_amdgcn_mfma_f32_16x16x32_bf16(ah[i], bl[j], acc[i][j], 0, 0, 0);
                acc[i][j] = __builtin_amdgcn_mfma_f32_16x16x32_bf16(ah[i], bh[j], acc[i][j], 0, 0, 0);
            }
        if (it + 1 < NIT) {
            *(uint4*)&smem[nxt + o0]         = rh0;
            *(uint4*)&smem[nxt + o1]         = rh1;
            *(uint4*)&smem[nxt + 5120 + o0]  = rl0;
            *(uint4*)&smem[nxt + 5120 + o1]  = rl1;
            *(uint4*)&smem[nxt + 10240 + o0] = sh0;
            *(uint4*)&smem[nxt + 10240 + o1] = sh1;
            *(uint4*)&smem[nxt + 15360 + o0] = sl0;
            *(uint4*)&smem[nxt + 15360 + o1] = sl1;
        }
        __syncthreads();
    }

    float rs[4][4];
#pragma unroll
    for (int i = 0; i < 4; ++i)
#pragma unroll
        for (int r = 0; r < 4; ++r) rs[i][r] = 0.f;

#pragma unroll
    for (int j = 0; j < 4; ++j) {
        int m = m0 + coloff + j * 16 + l16;
        float sm = sqb[m];
#pragma unroll
        for (int i = 0; i < 4; ++i) {
#pragma unroll
            for (int r = 0; r < 4; ++r) {
                int n = n0 + rowoff + i * 16 + quad * 4 + r;
                float v = __expf(2.f * acc[i][j][r] - sqb[n] - sm);
                Ab[(size_t)n * NN + m] = f2bf(v);
                rs[i][r] += v;
            }
        }
    }
    int slot = (rest & 7) * 2 + (wave & 1);
#pragma unroll
    for (int i = 0; i < 4; ++i)
#pragma unroll
        for (int r = 0; r < 4; ++r) {
            float s = rs[i][r];
            s += __shfl_xor(s, 1);
            s += __shfl_xor(s, 2);
            s += __shfl_xor(s, 4);
            s += __shfl_xor(s, 8);
            if (l16 == 0)
                deg_part[((size_t)slot * BCv + b) * NN + n0 + rowoff + i * 16 + quad * 4 + r] = s;
        }
}

// dis[b][n] = rsqrt(sum of 16 deg partials); X0t[b][f][n0..] *= dis[n] in place.
// 1D grid 16*BC: b = L&(BC-1), n0 = (L>>bsh)*64.
__global__ __launch_bounds__(256) void disscale_kernel(
    ushort_t* __restrict__ Xt, const float* __restrict__ deg_part,
    float* __restrict__ dis, int Fp, int bsh, int BCv) {
    int L = blockIdx.x;
    int b = L & ((1 << bsh) - 1), n0 = (L >> bsh) * 64;
    int t = threadIdx.x;
    __shared__ float dloc[64];
    if (t < 64) {
        float s = 0.f;
#pragma unroll
        for (int k = 0; k < 16; ++k) s += deg_part[((size_t)k * BCv + b) * NN + n0 + t];
        float d = rsqrtf(s);
        dloc[t] = d;
        dis[(size_t)b * NN + n0 + t] = d;
    }
    __syncthreads();
    int lane = t & 63, fq = t >> 6;
    float d = dloc[lane];
    ushort_t* Xb = Xt + (size_t)b * Fp * NN + n0 + lane;
    for (int f = fq; f < Fp; f += 4) {
        size_t off = (size_t)f * NN;
        Xb[off] = f2bf(bf2f(Xb[off]) * d);
    }
}

// lx: acc[f][n] = sum_k in_t[f][k] * A[n][k]  (A raw symmetric), dbuf K-loop.
// in_t is node-scaled (S). Tile 128f x 64n, 4 waves, acc[2][4].
// mode0: out_t = S1 = xin - dn^2*acc; out_b = X1 = inv*xin - dn*acc.
// mode1: out_b = X2 = inv*(2*xin - x0) - 2*dn*acc.
// 1D grid ft*16*BC: b = L&(BC-1); rest = L>>bsh; f_tile = rest%ft; n_tile = rest/ft.
__global__ __launch_bounds__(256) void lx_kernel(
    const ushort_t* __restrict__ Abf, const float* __restrict__ dis,
    const ushort_t* __restrict__ in_t, const ushort_t* __restrict__ x0t,
    ushort_t* __restrict__ out_t, ushort_t* __restrict__ out_b,
    int F, int Fp, int mode, int ft, int bsh) {
    int t = threadIdx.x;
    int L = blockIdx.x;
    int b = L & ((1 << bsh) - 1);
    int rest = L >> bsh;
    int m0 = (rest % ft) * 128;   // f tile (128)
    int n0 = (rest / ft) * 64;    // n tile (64)
    const ushort_t* Ain = in_t + (size_t)b * Fp * NN;
    const ushort_t* Ab = Abf + (size_t)b * NN * NN;

    int lane = t & 63, quad = lane >> 4, l16 = lane & 15, wave = t >> 6;
    int rowoff = wave * 32;

    __shared__ __align__(16) ushort_t smem[15360];

    f32x4 acc[2][4];
#pragma unroll
    for (int i = 0; i < 2; ++i)
#pragma unroll
        for (int j = 0; j < 4; ++j) acc[i][j] = (f32x4){0.f, 0.f, 0.f, 0.f};

    int rr0 = t >> 2, kq = (t & 3) * 8;
    int rr1 = rr0 + 64;
    bool av0 = (m0 + rr0 < F), av1 = (m0 + rr1 < F);
    const ushort_t* pA0 = Ain + (size_t)(m0 + rr0) * NN + kq;
    const ushort_t* pA1 = Ain + (size_t)(m0 + rr1) * NN + kq;
    const ushort_t* pB0 = Ab + (size_t)(n0 + rr0) * NN + kq;
    int o0 = rr0 * 40 + kq, o1 = rr1 * 40 + kq;
    const uint4 z4 = make_uint4(0u, 0u, 0u, 0u);

    {
        *(uint4*)&smem[o0]        = av0 ? *(const uint4*)pA0 : z4;
        *(uint4*)&smem[o1]        = av1 ? *(const uint4*)pA1 : z4;
        *(uint4*)&smem[5120 + o0] = *(const uint4*)pB0;
    }
    __syncthreads();

    for (int it = 0; it < 32; ++it) {
        int cur = (it & 1) * 7680;
        int nxt = 7680 - cur;
        uint4 ra0, ra1, rb0;
        if (it < 31) {
            int k = (it + 1) * 32;
            ra0 = av0 ? *(const uint4*)(pA0 + k) : z4;
            ra1 = av1 ? *(const uint4*)(pA1 + k) : z4;
            rb0 = *(const uint4*)(pB0 + k);
        }
        ushort_t* AsP = smem + cur;
        ushort_t* BsP = AsP + 5120;
        bf16x8 af[2], bfv[4];
#pragma unroll
        for (int i = 0; i < 2; ++i)
            af[i] = *(const bf16x8*)&AsP[(rowoff + i * 16 + l16) * 40 + quad * 8];
#pragma unroll
        for (int j = 0; j < 4; ++j)
            bfv[j] = *(const bf16x8*)&BsP[(j * 16 + l16) * 40 + quad * 8];
#pragma unroll
        for (int i = 0; i < 2; ++i)
#pragma unroll
            for (int j = 0; j < 4; ++j)
                acc[i][j] = __builtin_amdgcn_mfma_f32_16x16x32_bf16(af[i], bfv[j], acc[i][j], 0, 0, 0);
        if (it < 31) {
            *(uint4*)&smem[nxt + o0]        = ra0;
            *(uint4*)&smem[nxt + o1]        = ra1;
            *(uint4*)&smem[nxt + 5120 + o0] = rb0;
        }
        __syncthreads();
    }

#pragma unroll
    for (int j = 0; j < 4; ++j) {
        int nl = j * 16 + l16;
        int n = n0 + nl;
        float dn = dis[(size_t)b * NN + n];
        float inv = 1.f / dn;
        float dn2 = dn * dn;
#pragma unroll
        for (int i = 0; i < 2; ++i) {
#pragma unroll
            for (int r = 0; r < 4; ++r) {
                int fl = rowoff + i * 16 + quad * 4 + r;
                int f = m0 + fl;
                float o = 0.f;
                if (f < F) {
                    float a = acc[i][j][r];
                    size_t off = (size_t)f * NN + n;
                    float xin = bf2f(Ain[off]);
                    if (mode == 0) {
                        out_t[(size_t)b * Fp * NN + off] = f2bf(xin - dn2 * a);
                        o = inv * xin - dn * a;
                    } else {
                        float x0 = bf2f(x0t[(size_t)b * Fp * NN + off]);
                        o = inv * (2.f * xin - x0) - 2.f * dn * a;
                    }
                }
                smem[nl * 128 + (((fl >> 3) ^ (nl & 7)) << 3) + (fl & 7)] = f2bf(o);
            }
        }
    }
    __syncthreads();
    for (int s2 = t; s2 < 1024; s2 += 256) {
        int nl = s2 >> 4, oct = s2 & 15;
        int fg = m0 + oct * 8;
        if (fg < Fp) {
            uint4 v = *(const uint4*)&smem[nl * 128 + ((oct ^ (nl & 7)) << 3)];
            *(uint4*)(out_b + ((size_t)b * NN + n0 + nl) * Fp + fg) = v;
        }
    }
}

// Out[r][g] = relu( sum_p Xp[r][:].Wt[p][g][:] + bias[g] ), dbuf over (p,k);
// layer3: fused maxpool. 1D grid n_g*8*BC: c=L&(BC-1); rest=L>>bsh;
// g=rest%n_g; r_tile = c*8 + rest/n_g.
__global__ __launch_bounds__(256) void proj_kernel(
    const ushort_t* __restrict__ X0, const ushort_t* __restrict__ X1,
    const ushort_t* __restrict__ X2, const ushort_t* __restrict__ Wt,
    const float* __restrict__ bias, float* __restrict__ O, float* __restrict__ pool,
    int Fp, int Fo, int b0, int n_g, int bsh) {
    int t = threadIdx.x;
    int L = blockIdx.x;
    int c = L & ((1 << bsh) - 1);
    int rest = L >> bsh;
    int g0 = (rest % n_g) * 128;
    int r0 = (c * 8 + rest / n_g) * 128;
    int lane = t & 63, quad = lane >> 4, l16 = lane & 15, wave = t >> 6;
    int rowoff = (wave >> 1) * 64, coloff = (wave & 1) * 64;

    __shared__ __align__(16) ushort_t smem[20480];
    f32x4 acc[4][4];
#pragma unroll
    for (int i = 0; i < 4; ++i)
#pragma unroll
        for (int j = 0; j < 4; ++j) acc[i][j] = (f32x4){0.f, 0.f, 0.f, 0.f};

    const ushort_t* Xs[3] = {X0, X1, X2};
    int rr0 = t >> 2, kq = (t & 3) * 8;
    int rr1 = rr0 + 64;
    int o0 = rr0 * 40 + kq, o1 = rr1 * 40 + kq;
    int nk = Fp >> 5;
    int NIT = 3 * nk;

    {
        *(uint4*)&smem[o0]        = *(const uint4*)(X0 + (size_t)(r0 + rr0) * Fp + kq);
        *(uint4*)&smem[o1]        = *(const uint4*)(X0 + (size_t)(r0 + rr1) * Fp + kq);
        *(uint4*)&smem[5120 + o0] = *(const uint4*)(Wt + (size_t)(g0 + rr0) * Fp + kq);
        *(uint4*)&smem[5120 + o1] = *(const uint4*)(Wt + (size_t)(g0 + rr1) * Fp + kq);
    }
    __syncthreads();

    for (int it = 0; it < NIT; ++it) {
        int cur = (it & 1) * 10240;
        int nxt = 10240 - cur;
        uint4 ra0, ra1, rb0, rb1;
        if (it + 1 < NIT) {
            int idx = it + 1;
            int p = idx / nk;
            int k = (idx - p * nk) * 32 + kq;
            const ushort_t* Xp = Xs[p];
            const ushort_t* Wp = Wt + (size_t)p * Fo * Fp;
            ra0 = *(const uint4*)(Xp + (size_t)(r0 + rr0) * Fp + k);
            ra1 = *(const uint4*)(Xp + (size_t)(r0 + rr1) * Fp + k);
            rb0 = *(const uint4*)(Wp + (size_t)(g0 + rr0) * Fp + k);
            rb1 = *(const uint4*)(Wp + (size_t)(g0 + rr1) * Fp + k);
        }
        ushort_t* AsP = smem + cur;
        ushort_t* BsP = smem + cur + 5120;
        bf16x8 af[4], bfv[4];
#pragma unroll
        for (int i = 0; i < 4; ++i)
            af[i] = *(const bf16x8*)&AsP[(rowoff + i * 16 + l16) * 40 + quad * 8];
#pragma unroll
        for (int j = 0; j < 4; ++j)
            bfv[j] = *(const bf16x8*)&BsP[(coloff + j * 16 + l16) * 40 + quad * 8];
#pragma unroll
        for (int i = 0; i < 4; ++i)
#pragma unroll
            for (int j = 0; j < 4; ++j)
                acc[i][j] = __builtin_amdgcn_mfma_f32_16x16x32_bf16(af[i], bfv[j], acc[i][j], 0, 0, 0);
        if (it + 1 < NIT) {
            *(uint4*)&smem[nxt + o0]        = ra0;
            *(uint4*)&smem[nxt + o1]        = ra1;
            *(uint4*)&smem[nxt + 5120 + o0] = rb0;
            *(uint4*)&smem[nxt + 5120 + o1] = rb1;
        }
        __syncthreads();
    }

    float bias_l[4];
#pragma unroll
    for (int j = 0; j < 4; ++j) bias_l[j] = bias[g0 + coloff + j * 16 + l16];

    if (O) {
#pragma unroll
        for (int i = 0; i < 4; ++i) {
#pragma unroll
            for (int r = 0; r < 4; ++r) {
                int row = r0 + rowoff + i * 16 + quad * 4 + r;
#pragma unroll
                for (int j = 0; j < 4; ++j) {
                    int g = g0 + coloff + j * 16 + l16;
                    O[(size_t)row * Fo + g] = fmaxf(acc[i][j][r] + bias_l[j], 0.f);
                }
            }
        }
    } else {
        float mj[4];
#pragma unroll
        for (int j = 0; j < 4; ++j) {
            float m = 0.f;
#pragma unroll
            for (int i = 0; i < 4; ++i)
#pragma unroll
                for (int r = 0; r < 4; ++r)
                    m = fmaxf(m, acc[i][j][r] + bias_l[j]);
            m = fmaxf(m, 0.f);
            m = fmaxf(m, __shfl_xor(m, 16));
            m = fmaxf(m, __shfl_xor(m, 32));
            mj[j] = m;
        }
        if (quad == 0) {
            int smp = b0 + (r0 >> 10);
#pragma unroll
            for (int j = 0; j < 4; ++j)
                atomicMax((int*)&pool[(size_t)smp * 1024 + g0 + coloff + j * 16 + l16],
                          __float_as_int(mj[j]));
        }
    }
}

// fc: block = (row, 64-col tile); 4 K-slices x 64 cols; LDS reduce.
__global__ __launch_bounds__(256) void fc_kernel(
    const float* __restrict__ In, const float* __restrict__ W,
    const float* __restrict__ bias, float* __restrict__ out,
    int K, int Nout, int relu) {
    int r = blockIdx.y;
    int c0 = blockIdx.x * 64;
    int t = threadIdx.x;
    int cl = t & 63, ks = t >> 6;
    int c = c0 + cl;
    int kchunk = K >> 2;
    int k0 = ks * kchunk, k1 = k0 + kchunk;
    float s = 0.f;
    if (c < Nout) {
        const float* ip = In + (size_t)r * K;
        const float* wp = W + c;
#pragma unroll 4
        for (int k = k0; k < k1; ++k) s += ip[k] * wp[(size_t)k * Nout];
    }
    __shared__ float red[4][64];
    red[ks][cl] = s;
    __syncthreads();
    if (t < 64 && c0 + t < Nout) {
        float v = red[0][t] + red[1][t] + red[2][t] + red[3][t] + bias[c0 + t];
        if (relu) v = fmaxf(v, 0.f);
        out[(size_t)r * Nout + c0 + t] = v;
    }
}

// ---------------------------------------------------------------------------
extern "C" void kernel_launch(void* const* d_in, const int* in_sizes, int n_in,
                              void* d_out, int out_size, void* d_ws, size_t ws_size,
                              hipStream_t stream) {
    const float* x    = (const float*)d_in[0];
    const float* W1   = (const float*)d_in[1];
    const float* b1   = (const float*)d_in[2];
    const float* W2   = (const float*)d_in[3];
    const float* b2   = (const float*)d_in[4];
    const float* W3   = (const float*)d_in[5];
    const float* b3   = (const float*)d_in[6];
    const float* fc1w = (const float*)d_in[7];
    const float* fc1b = (const float*)d_in[8];
    const float* fc2w = (const float*)d_in[9];
    const float* fc2b = (const float*)d_in[10];
    const float* fc3w = (const float*)d_in[11];
    const float* fc3b = (const float*)d_in[12];
    float* out = (float*)d_out;

    auto need = [](size_t BCv) -> size_t {
        size_t us = (size_t)BCv * 1024;
        return 2 * (us * 1024) + 10 * (us * 512) + 2 * 1781760ull +
               4 * (us * 128) + 4 * (us * 512) + 4 * us + 64 * us + 4 * us +
               4 * (32768ull + 16384 + 4096) + 256;
    };
    int BCv = (ws_size >= need(16)) ? 16 : 8;
    int NCH = 32 / BCv;
    int bsh = (BCv == 16) ? 4 : 3;

    size_t usc = (size_t)BCv * 1024;
    size_t Asz = usc * 1024;           // ushorts
    size_t SLv = usc * 512;            // ushorts
    ushort_t* Abf  = (ushort_t*)d_ws;
    ushort_t* X0hi = Abf + Asz;
    ushort_t* X0lo = X0hi + SLv;       // aliases X2b (disjoint lifetime)
    ushort_t* X0t  = X0lo + SLv;
    ushort_t* X1t  = X0t + SLv;
    ushort_t* X1b  = X1t + SLv;
    ushort_t* Wt   = X1b + SLv;        // 1781760 ushorts
    float* O1   = (float*)(Wt + 1781760);
    float* O2   = O1 + usc * 128;
    float* sq   = O2 + usc * 512;
    float* degp = sq + usc;            // 16*BC*NN
    float* dis  = degp + 16 * usc;     // BC*NN
    float* pool = dis + usc;           // 32*1024
    float* f1   = pool + 32768;
    float* f2   = f1 + 16384;
    ushort_t* X2b = X0lo;              // alias

    wconvT_kernel<<<dim3(2, 1, 3), 256, 0, stream>>>(W1, Wt, 6, 128, 32);
    wconvT_kernel<<<dim3(8, 2, 3), 256, 0, stream>>>(W2, Wt + 12288, 128, 512, 128);
    wconvT_kernel<<<dim3(16, 8, 3), 256, 0, stream>>>(W3, Wt + 208896, 512, 1024, 512);
    zero_kernel<<<128, 256, 0, stream>>>(pool, 32768);

    for (int c = 0; c < NCH; ++c) {
        int b0 = c * BCv;
        struct LayerDef {
            const float* X; int F, Fp, Fo;
            const ushort_t* Wtl; const float* bias; float* O;
        };
        LayerDef L[3] = {
            { x + (size_t)b0 * NN * 6, 6,   32,  128,  Wt,          b1, O1 },
            { O1,                      128, 128, 512,  Wt + 12288,  b2, O2 },
            { O2,                      512, 512, 1024, Wt + 208896, b3, nullptr },
        };
        for (int li = 0; li < 3; ++li) {
            LayerDef& Ld = L[li];
            int F = Ld.F, Fp = Ld.Fp;
            int ft = (F + 127) / 128;
            int n_g = Ld.Fo / 128;
            prep2_kernel<<<16 * BCv, 256, 0, stream>>>(Ld.X, X0hi, X0lo, X0t, sq, F, Fp, bsh);
            adj_kernel<<<64 * BCv, 256, 0, stream>>>(X0hi, X0lo, sq, Abf, degp, Fp, bsh, BCv);
            disscale_kernel<<<16 * BCv, 256, 0, stream>>>(X0t, degp, dis, Fp, bsh, BCv);
            lx_kernel<<<ft * 16 * BCv, 256, 0, stream>>>(
                Abf, dis, X0t, nullptr, X1t, X1b, F, Fp, 0, ft, bsh);
            lx_kernel<<<ft * 16 * BCv, 256, 0, stream>>>(
                Abf, dis, X1t, X0t, nullptr, X2b, F, Fp, 1, ft, bsh);
            proj_kernel<<<n_g * 8 * BCv, 256, 0, stream>>>(
                X0hi, X1b, X2b, Ld.Wtl, Ld.bias, Ld.O, pool, Fp, Ld.Fo, b0, n_g, bsh);
        }
    }

    fc_kernel<<<dim3(8, 32), 256, 0, stream>>>(pool, fc1w, fc1b, f1, 1024, 512, 1);
    fc_kernel<<<dim3(2, 32), 256, 0, stream>>>(f1, fc2w, fc2b, f2, 512, 128, 1);
    fc_kernel<<<dim3(1, 32), 256, 0, stream>>>(f2, fc3w, fc3b, out, 128, 40, 0);
}

// Round 14
// 1035.081 us; speedup vs baseline: 1.2450x; 1.0211x over previous
//
#include <hip/hip_runtime.h>
#include <cstddef>

// ---------------------------------------------------------------------------
// ChebNet MFMA bf16: B=32, N=1024, layers 6->128->512->1024 (K=3), maxpool,
// FC 1024->512->128->40. BC=16 x 2 chunks (~160 MB ws) when ws allows, else 8x4.
// Per layer: prep2 -> adj -> disscale -> lx1 -> lx2 -> proj.
// A RAW bf16 (D folded into lx epilogues). lx/proj K-loops: 2-stage LDS dbuf
// with DEPTH-2 register prefetch using two explicitly-named sets (X/Y) and a
// manually 2x-unrolled pair loop (runtime-indexed sets spilled in r8).
// 1D grids, XCD-aware decode (sample = L & (BC-1)).
// ---------------------------------------------------------------------------

#define NN 1024

typedef unsigned short ushort_t;
typedef __bf16 bf16x8 __attribute__((ext_vector_type(8)));
typedef float f32x4 __attribute__((ext_vector_type(4)));

__device__ inline ushort_t f2bf(float f) {
    unsigned int u = __float_as_uint(f);
    u = (u + 0x7fffu + ((u >> 16) & 1u)) >> 16;
    return (ushort_t)u;
}
__device__ inline float bf2f(ushort_t s) {
    return __uint_as_float(((unsigned int)s) << 16);
}

__global__ void zero_kernel(float* __restrict__ p, int n) {
    int i = blockIdx.x * blockDim.x + threadIdx.x;
    if (i < n) p[i] = 0.f;
}

// W[p][Fi][Fo] fp32 -> Wt[p][Fo][Ks] bf16, LDS-tiled transpose, zero-pad K.
__global__ __launch_bounds__(256) void wconvT_kernel(
    const float* __restrict__ W, ushort_t* __restrict__ Wt, int Fi, int Fo, int Ks) {
    int p = blockIdx.z;
    int k0 = blockIdx.y * 64, g0 = blockIdx.x * 64;
    __shared__ float T[64][65];
    int t = threadIdx.x;
#pragma unroll
    for (int q = 0; q < 16; ++q) {
        int kr = (t >> 6) + 4 * q, gc = t & 63;
        int k = k0 + kr, g = g0 + gc;
        T[kr][gc] = (k < Fi && g < Fo) ? W[((size_t)p * Fi + k) * Fo + g] : 0.f;
    }
    __syncthreads();
#pragma unroll
    for (int q = 0; q < 16; ++q) {
        int gr = (t >> 6) + 4 * q, kc = t & 63;
        int g = g0 + gr, k = k0 + kc;
        if (g < Fo && k < Ks)
            Wt[((size_t)p * Fo + g) * Ks + k] = f2bf(T[kc][gr]);
    }
}

// Fused: hi/lo bf16 split (row-major, pad to Fp), transpose Xt, sq.
__global__ __launch_bounds__(256) void prep2_kernel(
    const float* __restrict__ X, ushort_t* __restrict__ hi, ushort_t* __restrict__ lo,
    ushort_t* __restrict__ Xt, float* __restrict__ sq, int F, int Fp, int bsh) {
    int L = blockIdx.x;
    int b = L & ((1 << bsh) - 1), n0 = (L >> bsh) * 64;
    int t = threadIdx.x;
    __shared__ float T[64][65];
    __shared__ float red[4][64];
    const float* Xb = X + ((size_t)b * NN + n0) * F;
    float sacc = 0.f;

    for (int f0 = 0; f0 < Fp; f0 += 64) {
        __syncthreads();
#pragma unroll
        for (int p = 0; p < 16; ++p) {
            int nr = (t >> 6) + 4 * p, fc = t & 63;
            int f = f0 + fc;
            T[nr][fc] = (f < F) ? Xb[(size_t)nr * F + f] : 0.f;
        }
        __syncthreads();
#pragma unroll
        for (int p = 0; p < 16; ++p) {
            int nr = (t >> 6) + 4 * p, fc = t & 63;
            int f = f0 + fc;
            if (f < Fp) {
                float x = T[nr][fc];
                ushort_t h = f2bf(x);
                size_t off = ((size_t)b * NN + n0 + nr) * Fp + f;
                hi[off] = h;
                lo[off] = f2bf(x - bf2f(h));
            }
        }
#pragma unroll
        for (int p = 0; p < 16; ++p) {
            int fr = (t >> 6) + 4 * p;
            int f = f0 + fr;
            if (f < F)
                Xt[((size_t)b * Fp + f) * NN + n0 + (t & 63)] = f2bf(T[t & 63][fr]);
        }
        {
            int nl = t & 63, fq = t >> 6;
#pragma unroll
            for (int fc = 0; fc < 16; ++fc) {
                float v = T[nl][fq * 16 + fc];
                sacc += v * v;
            }
        }
    }
    red[t >> 6][t & 63] = sacc;
    __syncthreads();
    if (t < 64)
        sq[(size_t)b * NN + n0 + t] = red[0][t] + red[1][t] + red[2][t] + red[3][t];
}

// A[b,n,m] = exp(2 x_n.x_m - sq_n - sq_m) -> bf16 (split hi/lo MFMA), dbuf;
// degree partials deg_part[slot][b][n], slot = m_tile*2+(wave&1).
__global__ __launch_bounds__(256) void adj_kernel(
    const ushort_t* __restrict__ hi, const ushort_t* __restrict__ lo,
    const float* __restrict__ sq, ushort_t* __restrict__ Abf,
    float* __restrict__ deg_part, int Fp, int bsh, int BCv) {
    int t = threadIdx.x;
    int L = blockIdx.x;
    int b = L & ((1 << bsh) - 1);
    int rest = L >> bsh;
    int m0 = (rest & 7) * 128, n0 = (rest >> 3) * 128;
    const ushort_t* Hb = hi + (size_t)b * NN * Fp;
    const ushort_t* Lb = lo + (size_t)b * NN * Fp;
    ushort_t* Ab = Abf + (size_t)b * NN * NN;
    const float* sqb = sq + (size_t)b * NN;

    int lane = t & 63, quad = lane >> 4, l16 = lane & 15, wave = t >> 6;
    int rowoff = (wave >> 1) * 64, coloff = (wave & 1) * 64;

    __shared__ __align__(16) ushort_t smem[40960];

    f32x4 acc[4][4];
#pragma unroll
    for (int i = 0; i < 4; ++i)
#pragma unroll
        for (int j = 0; j < 4; ++j) acc[i][j] = (f32x4){0.f, 0.f, 0.f, 0.f};

    int rr0 = t >> 2, kq = (t & 3) * 8;
    int rr1 = rr0 + 64;
    const ushort_t* pAh0 = Hb + (size_t)(n0 + rr0) * Fp + kq;
    const ushort_t* pAh1 = Hb + (size_t)(n0 + rr1) * Fp + kq;
    const ushort_t* pAl0 = Lb + (size_t)(n0 + rr0) * Fp + kq;
    const ushort_t* pAl1 = Lb + (size_t)(n0 + rr1) * Fp + kq;
    const ushort_t* pBh0 = Hb + (size_t)(m0 + rr0) * Fp + kq;
    const ushort_t* pBh1 = Hb + (size_t)(m0 + rr1) * Fp + kq;
    const ushort_t* pBl0 = Lb + (size_t)(m0 + rr0) * Fp + kq;
    const ushort_t* pBl1 = Lb + (size_t)(m0 + rr1) * Fp + kq;
    int o0 = rr0 * 40 + kq, o1 = rr1 * 40 + kq;

    {
        *(uint4*)&smem[o0]         = *(const uint4*)pAh0;
        *(uint4*)&smem[o1]         = *(const uint4*)pAh1;
        *(uint4*)&smem[5120 + o0]  = *(const uint4*)pAl0;
        *(uint4*)&smem[5120 + o1]  = *(const uint4*)pAl1;
        *(uint4*)&smem[10240 + o0] = *(const uint4*)pBh0;
        *(uint4*)&smem[10240 + o1] = *(const uint4*)pBh1;
        *(uint4*)&smem[15360 + o0] = *(const uint4*)pBl0;
        *(uint4*)&smem[15360 + o1] = *(const uint4*)pBl1;
    }
    __syncthreads();

    int NIT = Fp >> 5;
    for (int it = 0; it < NIT; ++it) {
        int cur = (it & 1) * 20480;
        int nxt = 20480 - cur;
        uint4 rh0, rh1, rl0, rl1, sh0, sh1, sl0, sl1;
        if (it + 1 < NIT) {
            int k = (it + 1) * 32;
            rh0 = *(const uint4*)(pAh0 + k); rh1 = *(const uint4*)(pAh1 + k);
            rl0 = *(const uint4*)(pAl0 + k); rl1 = *(const uint4*)(pAl1 + k);
            sh0 = *(const uint4*)(pBh0 + k); sh1 = *(const uint4*)(pBh1 + k);
            sl0 = *(const uint4*)(pBl0 + k); sl1 = *(const uint4*)(pBl1 + k);
        }
        ushort_t* Ah = smem + cur;
        ushort_t* Al = smem + cur + 5120;
        ushort_t* Bh = smem + cur + 10240;
        ushort_t* Bl = smem + cur + 15360;
        bf16x8 ah[4], al[4], bh[4], bl[4];
#pragma unroll
        for (int i = 0; i < 4; ++i) {
            ah[i] = *(const bf16x8*)&Ah[(rowoff + i * 16 + l16) * 40 + quad * 8];
            al[i] = *(const bf16x8*)&Al[(rowoff + i * 16 + l16) * 40 + quad * 8];
        }
#pragma unroll
        for (int j = 0; j < 4; ++j) {
            bh[j] = *(const bf16x8*)&Bh[(coloff + j * 16 + l16) * 40 + quad * 8];
            bl[j] = *(const bf16x8*)&Bl[(coloff + j * 16 + l16) * 40 + quad * 8];
        }
#pragma unroll
        for (int i = 0; i < 4; ++i)
#pragma unroll
            for (int j = 0; j < 4; ++j) {
                acc[i][j] = __builtin_amdgcn_mfma_f32_16x16x32_bf16(al[i], bh[j], acc[i][j], 0, 0, 0);
                acc[i][j] = __builtin_amdgcn_mfma_f32_16x16x32_bf16(ah[i], bl[j], acc[i][j], 0, 0, 0);
                acc[i][j] = __builtin_amdgcn_mfma_f32_16x16x32_bf16(ah[i], bh[j], acc[i][j], 0, 0, 0);
            }
        if (it + 1 < NIT) {
            *(uint4*)&smem[nxt + o0]         = rh0;
            *(uint4*)&smem[nxt + o1]         = rh1;
            *(uint4*)&smem[nxt + 5120 + o0]  = rl0;
            *(uint4*)&smem[nxt + 5120 + o1]  = rl1;
            *(uint4*)&smem[nxt + 10240 + o0] = sh0;
            *(uint4*)&smem[nxt + 10240 + o1] = sh1;
            *(uint4*)&smem[nxt + 15360 + o0] = sl0;
            *(uint4*)&smem[nxt + 15360 + o1] = sl1;
        }
        __syncthreads();
    }

    float rs[4][4];
#pragma unroll
    for (int i = 0; i < 4; ++i)
#pragma unroll
        for (int r = 0; r < 4; ++r) rs[i][r] = 0.f;

#pragma unroll
    for (int j = 0; j < 4; ++j) {
        int m = m0 + coloff + j * 16 + l16;
        float sm = sqb[m];
#pragma unroll
        for (int i = 0; i < 4; ++i) {
#pragma unroll
            for (int r = 0; r < 4; ++r) {
                int n = n0 + rowoff + i * 16 + quad * 4 + r;
                float v = __expf(2.f * acc[i][j][r] - sqb[n] - sm);
                Ab[(size_t)n * NN + m] = f2bf(v);
                rs[i][r] += v;
            }
        }
    }
    int slot = (rest & 7) * 2 + (wave & 1);
#pragma unroll
    for (int i = 0; i < 4; ++i)
#pragma unroll
        for (int r = 0; r < 4; ++r) {
            float s = rs[i][r];
            s += __shfl_xor(s, 1);
            s += __shfl_xor(s, 2);
            s += __shfl_xor(s, 4);
            s += __shfl_xor(s, 8);
            if (l16 == 0)
                deg_part[((size_t)slot * BCv + b) * NN + n0 + rowoff + i * 16 + quad * 4 + r] = s;
        }
}

// dis[b][n] = rsqrt(sum of 16 deg partials); X0t[b][f][n0..] *= dis[n] in place.
__global__ __launch_bounds__(256) void disscale_kernel(
    ushort_t* __restrict__ Xt, const float* __restrict__ deg_part,
    float* __restrict__ dis, int Fp, int bsh, int BCv) {
    int L = blockIdx.x;
    int b = L & ((1 << bsh) - 1), n0 = (L >> bsh) * 64;
    int t = threadIdx.x;
    __shared__ float dloc[64];
    if (t < 64) {
        float s = 0.f;
#pragma unroll
        for (int k = 0; k < 16; ++k) s += deg_part[((size_t)k * BCv + b) * NN + n0 + t];
        float d = rsqrtf(s);
        dloc[t] = d;
        dis[(size_t)b * NN + n0 + t] = d;
    }
    __syncthreads();
    int lane = t & 63, fq = t >> 6;
    float d = dloc[lane];
    ushort_t* Xb = Xt + (size_t)b * Fp * NN + n0 + lane;
    for (int f = fq; f < Fp; f += 4) {
        size_t off = (size_t)f * NN;
        Xb[off] = f2bf(bf2f(Xb[off]) * d);
    }
}

// lx: acc[f][n] = sum_k in_t[f][k] * A[n][k]  (A raw symmetric).
// Depth-2 reg prefetch (X/Y named sets) over 2 LDS stages, pair-unrolled.
// Tile 128f x 64n, 4 waves, acc[2][4].  NIT = 32 (even).
// mode0: out_t = xin - dn^2*acc; out_b = inv*xin - dn*acc.
// mode1: out_b = inv*(2*xin - x0) - 2*dn*acc.
__global__ __launch_bounds__(256) void lx_kernel(
    const ushort_t* __restrict__ Abf, const float* __restrict__ dis,
    const ushort_t* __restrict__ in_t, const ushort_t* __restrict__ x0t,
    ushort_t* __restrict__ out_t, ushort_t* __restrict__ out_b,
    int F, int Fp, int mode, int ft, int bsh) {
    int t = threadIdx.x;
    int L = blockIdx.x;
    int b = L & ((1 << bsh) - 1);
    int rest = L >> bsh;
    int m0 = (rest % ft) * 128;   // f tile (128)
    int n0 = (rest / ft) * 64;    // n tile (64)
    const ushort_t* Ain = in_t + (size_t)b * Fp * NN;
    const ushort_t* Ab = Abf + (size_t)b * NN * NN;

    int lane = t & 63, quad = lane >> 4, l16 = lane & 15, wave = t >> 6;
    int rowoff = wave * 32;

    __shared__ __align__(16) ushort_t smem[15360];

    f32x4 acc[2][4];
#pragma unroll
    for (int i = 0; i < 2; ++i)
#pragma unroll
        for (int j = 0; j < 4; ++j) acc[i][j] = (f32x4){0.f, 0.f, 0.f, 0.f};

    int rr0 = t >> 2, kq = (t & 3) * 8;
    int rr1 = rr0 + 64;
    bool av0 = (m0 + rr0 < F), av1 = (m0 + rr1 < F);
    const ushort_t* pA0 = Ain + (size_t)(m0 + rr0) * NN + kq;
    const ushort_t* pA1 = Ain + (size_t)(m0 + rr1) * NN + kq;
    const ushort_t* pB0 = Ab + (size_t)(n0 + rr0) * NN + kq;
    int o0 = rr0 * 40 + kq, o1 = rr1 * 40 + kq;
    const uint4 z4 = make_uint4(0u, 0u, 0u, 0u);

#define LX_LOAD(ci, A0, A1, B0)                                     \
    {                                                               \
        int k_ = (ci) * 32;                                         \
        A0 = av0 ? *(const uint4*)(pA0 + k_) : z4;                  \
        A1 = av1 ? *(const uint4*)(pA1 + k_) : z4;                  \
        B0 = *(const uint4*)(pB0 + k_);                             \
    }
#define LX_STORE(NXT, A0, A1, B0)                                   \
    {                                                               \
        *(uint4*)&smem[(NXT) + o0]        = A0;                     \
        *(uint4*)&smem[(NXT) + o1]        = A1;                     \
        *(uint4*)&smem[(NXT) + 5120 + o0] = B0;                     \
    }
#define LX_COMPUTE(CUR)                                                         \
    {                                                                           \
        ushort_t* AsP = smem + (CUR);                                           \
        ushort_t* BsP = AsP + 5120;                                             \
        bf16x8 af[2], bfv[4];                                                   \
        _Pragma("unroll")                                                       \
        for (int i = 0; i < 2; ++i)                                             \
            af[i] = *(const bf16x8*)&AsP[(rowoff + i * 16 + l16) * 40 + quad * 8]; \
        _Pragma("unroll")                                                       \
        for (int j = 0; j < 4; ++j)                                             \
            bfv[j] = *(const bf16x8*)&BsP[(j * 16 + l16) * 40 + quad * 8];      \
        _Pragma("unroll")                                                       \
        for (int i = 0; i < 2; ++i)                                             \
            _Pragma("unroll")                                                   \
            for (int j = 0; j < 4; ++j)                                         \
                acc[i][j] = __builtin_amdgcn_mfma_f32_16x16x32_bf16(af[i], bfv[j], acc[i][j], 0, 0, 0); \
    }

    uint4 xa0, xa1, xb0, ya0, ya1, yb0;
    {
        uint4 t0, t1, t2;
        LX_LOAD(0, t0, t1, t2);
        LX_LOAD(1, xa0, xa1, xb0);
        LX_LOAD(2, ya0, ya1, yb0);
        LX_STORE(0, t0, t1, t2);
    }
    __syncthreads();

    for (int pp = 0; pp < 16; ++pp) {
        int k0i = 2 * pp;
        // even iter: compute stage0, store X (slice k0i+1) -> stage1, refill X
        LX_COMPUTE(0);
        LX_STORE(7680, xa0, xa1, xb0);
        {
            int ci = k0i + 3; if (ci > 31) ci = 31;
            LX_LOAD(ci, xa0, xa1, xb0);
        }
        __syncthreads();
        // odd iter: compute stage1, store Y (slice k0i+2) -> stage0, refill Y
        LX_COMPUTE(7680);
        LX_STORE(0, ya0, ya1, yb0);
        {
            int ci = k0i + 4; if (ci > 31) ci = 31;
            LX_LOAD(ci, ya0, ya1, yb0);
        }
        __syncthreads();
    }
#undef LX_LOAD
#undef LX_STORE
#undef LX_COMPUTE

#pragma unroll
    for (int j = 0; j < 4; ++j) {
        int nl = j * 16 + l16;
        int n = n0 + nl;
        float dn = dis[(size_t)b * NN + n];
        float inv = 1.f / dn;
        float dn2 = dn * dn;
#pragma unroll
        for (int i = 0; i < 2; ++i) {
#pragma unroll
            for (int r = 0; r < 4; ++r) {
                int fl = rowoff + i * 16 + quad * 4 + r;
                int f = m0 + fl;
                float o = 0.f;
                if (f < F) {
                    float a = acc[i][j][r];
                    size_t off = (size_t)f * NN + n;
                    float xin = bf2f(Ain[off]);
                    if (mode == 0) {
                        out_t[(size_t)b * Fp * NN + off] = f2bf(xin - dn2 * a);
                        o = inv * xin - dn * a;
                    } else {
                        float x0 = bf2f(x0t[(size_t)b * Fp * NN + off]);
                        o = inv * (2.f * xin - x0) - 2.f * dn * a;
                    }
                }
                smem[nl * 128 + (((fl >> 3) ^ (nl & 7)) << 3) + (fl & 7)] = f2bf(o);
            }
        }
    }
    __syncthreads();
    for (int s2 = t; s2 < 1024; s2 += 256) {
        int nl = s2 >> 4, oct = s2 & 15;
        int fg = m0 + oct * 8;
        if (fg < Fp) {
            uint4 v = *(const uint4*)&smem[nl * 128 + ((oct ^ (nl & 7)) << 3)];
            *(uint4*)(out_b + ((size_t)b * NN + n0 + nl) * Fp + fg) = v;
        }
    }
}

// Out[r][g] = relu( sum_p Xp[r][:].Wt[p][g][:] + bias[g] ).
// Depth-2 reg prefetch (X/Y named sets) over 2 LDS stages, pair-unrolled
// over combined (p,k) index; odd NIT handled by tail compute.
// layer3: fused maxpool. 1D grid n_g*8*BC.
__global__ __launch_bounds__(256) void proj_kernel(
    const ushort_t* __restrict__ X0, const ushort_t* __restrict__ X1,
    const ushort_t* __restrict__ X2, const ushort_t* __restrict__ Wt,
    const float* __restrict__ bias, float* __restrict__ O, float* __restrict__ pool,
    int Fp, int Fo, int b0, int n_g, int bsh) {
    int t = threadIdx.x;
    int L = blockIdx.x;
    int c = L & ((1 << bsh) - 1);
    int rest = L >> bsh;
    int g0 = (rest % n_g) * 128;
    int r0 = (c * 8 + rest / n_g) * 128;
    int lane = t & 63, quad = lane >> 4, l16 = lane & 15, wave = t >> 6;
    int rowoff = (wave >> 1) * 64, coloff = (wave & 1) * 64;

    __shared__ __align__(16) ushort_t smem[20480];
    f32x4 acc[4][4];
#pragma unroll
    for (int i = 0; i < 4; ++i)
#pragma unroll
        for (int j = 0; j < 4; ++j) acc[i][j] = (f32x4){0.f, 0.f, 0.f, 0.f};

    const ushort_t* Xs[3] = {X0, X1, X2};
    int rr0 = t >> 2, kq = (t & 3) * 8;
    int rr1 = rr0 + 64;
    int o0 = rr0 * 40 + kq, o1 = rr1 * 40 + kq;
    int nk = Fp >> 5;
    int NIT = 3 * nk;
    size_t FoFp = (size_t)Fo * Fp;

#define PJ_LOAD(ci, A0, A1, B0, B1)                                   \
    {                                                                 \
        int p_ = (ci) / nk;                                           \
        int k_ = ((ci) - p_ * nk) * 32 + kq;                          \
        const ushort_t* Xp_ = Xs[p_];                                 \
        const ushort_t* Wp_ = Wt + (size_t)p_ * FoFp;                 \
        A0 = *(const uint4*)(Xp_ + (size_t)(r0 + rr0) * Fp + k_);     \
        A1 = *(const uint4*)(Xp_ + (size_t)(r0 + rr1) * Fp + k_);     \
        B0 = *(const uint4*)(Wp_ + (size_t)(g0 + rr0) * Fp + k_);     \
        B1 = *(const uint4*)(Wp_ + (size_t)(g0 + rr1) * Fp + k_);     \
    }
#define PJ_STORE(NXT, A0, A1, B0, B1)                                 \
    {                                                                 \
        *(uint4*)&smem[(NXT) + o0]        = A0;                       \
        *(uint4*)&smem[(NXT) + o1]        = A1;                       \
        *(uint4*)&smem[(NXT) + 5120 + o0] = B0;                       \
        *(uint4*)&smem[(NXT) + 5120 + o1] = B1;                       \
    }
#define PJ_COMPUTE(CUR)                                                          \
    {                                                                            \
        ushort_t* AsP = smem + (CUR);                                            \
        ushort_t* BsP = AsP + 5120;                                              \
        bf16x8 af[4], bfv[4];                                                    \
        _Pragma("unroll")                                                        \
        for (int i = 0; i < 4; ++i)                                              \
            af[i] = *(const bf16x8*)&AsP[(rowoff + i * 16 + l16) * 40 + quad * 8];  \
        _Pragma("unroll")                                                        \
        for (int j = 0; j < 4; ++j)                                              \
            bfv[j] = *(const bf16x8*)&BsP[(coloff + j * 16 + l16) * 40 + quad * 8]; \
        _Pragma("unroll")                                                        \
        for (int i = 0; i < 4; ++i)                                              \
            _Pragma("unroll")                                                    \
            for (int j = 0; j < 4; ++j)                                          \
                acc[i][j] = __builtin_amdgcn_mfma_f32_16x16x32_bf16(af[i], bfv[j], acc[i][j], 0, 0, 0); \
    }

    uint4 xa0, xa1, xb0, xb1, ya0, ya1, yb0, yb1;
    {
        uint4 t0, t1, t2, t3;
        PJ_LOAD(0, t0, t1, t2, t3);
        PJ_LOAD(1, xa0, xa1, xb0, xb1);
        PJ_LOAD(2, ya0, ya1, yb0, yb1);
        PJ_STORE(0, t0, t1, t2, t3);
    }
    __syncthreads();

    int pairs = NIT >> 1;
    for (int pp = 0; pp < pairs; ++pp) {
        int k0i = 2 * pp;
        PJ_COMPUTE(0);
        PJ_STORE(10240, xa0, xa1, xb0, xb1);
        {
            int ci = k0i + 3; if (ci > NIT - 1) ci = NIT - 1;
            PJ_LOAD(ci, xa0, xa1, xb0, xb1);
        }
        __syncthreads();
        PJ_COMPUTE(10240);
        PJ_STORE(0, ya0, ya1, yb0, yb1);
        {
            int ci = k0i + 4; if (ci > NIT - 1) ci = NIT - 1;
            PJ_LOAD(ci, ya0, ya1, yb0, yb1);
        }
        __syncthreads();
    }
    if (NIT & 1) {
        PJ_COMPUTE(0);   // final iter (NIT odd -> stage (NIT-1)&1 == 0)
    }
#undef PJ_LOAD
#undef PJ_STORE
#undef PJ_COMPUTE

    float bias_l[4];
#pragma unroll
    for (int j = 0; j < 4; ++j) bias_l[j] = bias[g0 + coloff + j * 16 + l16];

    if (O) {
#pragma unroll
        for (int i = 0; i < 4; ++i) {
#pragma unroll
            for (int r = 0; r < 4; ++r) {
                int row = r0 + rowoff + i * 16 + quad * 4 + r;
#pragma unroll
                for (int j = 0; j < 4; ++j) {
                    int g = g0 + coloff + j * 16 + l16;
                    O[(size_t)row * Fo + g] = fmaxf(acc[i][j][r] + bias_l[j], 0.f);
                }
            }
        }
    } else {
        float mj[4];
#pragma unroll
        for (int j = 0; j < 4; ++j) {
            float m = 0.f;
#pragma unroll
            for (int i = 0; i < 4; ++i)
#pragma unroll
                for (int r = 0; r < 4; ++r)
                    m = fmaxf(m, acc[i][j][r] + bias_l[j]);
            m = fmaxf(m, 0.f);
            m = fmaxf(m, __shfl_xor(m, 16));
            m = fmaxf(m, __shfl_xor(m, 32));
            mj[j] = m;
        }
        if (quad == 0) {
            int smp = b0 + (r0 >> 10);
#pragma unroll
            for (int j = 0; j < 4; ++j)
                atomicMax((int*)&pool[(size_t)smp * 1024 + g0 + coloff + j * 16 + l16],
                          __float_as_int(mj[j]));
        }
    }
}

// fc: block = (row, 64-col tile); 4 K-slices x 64 cols; LDS reduce.
__global__ __launch_bounds__(256) void fc_kernel(
    const float* __restrict__ In, const float* __restrict__ W,
    const float* __restrict__ bias, float* __restrict__ out,
    int K, int Nout, int relu) {
    int r = blockIdx.y;
    int c0 = blockIdx.x * 64;
    int t = threadIdx.x;
    int cl = t & 63, ks = t >> 6;
    int c = c0 + cl;
    int kchunk = K >> 2;
    int k0 = ks * kchunk, k1 = k0 + kchunk;
    float s = 0.f;
    if (c < Nout) {
        const float* ip = In + (size_t)r * K;
        const float* wp = W + c;
#pragma unroll 4
        for (int k = k0; k < k1; ++k) s += ip[k] * wp[(size_t)k * Nout];
    }
    __shared__ float red[4][64];
    red[ks][cl] = s;
    __syncthreads();
    if (t < 64 && c0 + t < Nout) {
        float v = red[0][t] + red[1][t] + red[2][t] + red[3][t] + bias[c0 + t];
        if (relu) v = fmaxf(v, 0.f);
        out[(size_t)r * Nout + c0 + t] = v;
    }
}

// ---------------------------------------------------------------------------
extern "C" void kernel_launch(void* const* d_in, const int* in_sizes, int n_in,
                              void* d_out, int out_size, void* d_ws, size_t ws_size,
                              hipStream_t stream) {
    const float* x    = (const float*)d_in[0];
    const float* W1   = (const float*)d_in[1];
    const float* b1   = (const float*)d_in[2];
    const float* W2   = (const float*)d_in[3];
    const float* b2   = (const float*)d_in[4];
    const float* W3   = (const float*)d_in[5];
    const float* b3   = (const float*)d_in[6];
    const float* fc1w = (const float*)d_in[7];
    const float* fc1b = (const float*)d_in[8];
    const float* fc2w = (const float*)d_in[9];
    const float* fc2b = (const float*)d_in[10];
    const float* fc3w = (const float*)d_in[11];
    const float* fc3b = (const float*)d_in[12];
    float* out = (float*)d_out;

    auto need = [](size_t BCv) -> size_t {
        size_t us = (size_t)BCv * 1024;
        return 2 * (us * 1024) + 10 * (us * 512) + 2 * 1781760ull +
               4 * (us * 128) + 4 * (us * 512) + 4 * us + 64 * us + 4 * us +
               4 * (32768ull + 16384 + 4096) + 256;
    };
    int BCv = (ws_size >= need(16)) ? 16 : 8;
    int NCH = 32 / BCv;
    int bsh = (BCv == 16) ? 4 : 3;

    size_t usc = (size_t)BCv * 1024;
    size_t Asz = usc * 1024;           // ushorts
    size_t SLv = usc * 512;            // ushorts
    ushort_t* Abf  = (ushort_t*)d_ws;
    ushort_t* X0hi = Abf + Asz;
    ushort_t* X0lo = X0hi + SLv;       // aliases X2b (disjoint lifetime)
    ushort_t* X0t  = X0lo + SLv;
    ushort_t* X1t  = X0t + SLv;
    ushort_t* X1b  = X1t + SLv;
    ushort_t* Wt   = X1b + SLv;        // 1781760 ushorts
    float* O1   = (float*)(Wt + 1781760);
    float* O2   = O1 + usc * 128;
    float* sq   = O2 + usc * 512;
    float* degp = sq + usc;            // 16*BC*NN
    float* dis  = degp + 16 * usc;     // BC*NN
    float* pool = dis + usc;           // 32*1024
    float* f1   = pool + 32768;
    float* f2   = f1 + 16384;
    ushort_t* X2b = X0lo;              // alias

    wconvT_kernel<<<dim3(2, 1, 3), 256, 0, stream>>>(W1, Wt, 6, 128, 32);
    wconvT_kernel<<<dim3(8, 2, 3), 256, 0, stream>>>(W2, Wt + 12288, 128, 512, 128);
    wconvT_kernel<<<dim3(16, 8, 3), 256, 0, stream>>>(W3, Wt + 208896, 512, 1024, 512);
    zero_kernel<<<128, 256, 0, stream>>>(pool, 32768);

    for (int c = 0; c < NCH; ++c) {
        int b0 = c * BCv;
        struct LayerDef {
            const float* X; int F, Fp, Fo;
            const ushort_t* Wtl; const float* bias; float* O;
        };
        LayerDef L[3] = {
            { x + (size_t)b0 * NN * 6, 6,   32,  128,  Wt,          b1, O1 },
            { O1,                      128, 128, 512,  Wt + 12288,  b2, O2 },
            { O2,                      512, 512, 1024, Wt + 208896, b3, nullptr },
        };
        for (int li = 0; li < 3; ++li) {
            LayerDef& Ld = L[li];
            int F = Ld.F, Fp = Ld.Fp;
            int ft = (F + 127) / 128;
            int n_g = Ld.Fo / 128;
            prep2_kernel<<<16 * BCv, 256, 0, stream>>>(Ld.X, X0hi, X0lo, X0t, sq, F, Fp, bsh);
            adj_kernel<<<64 * BCv, 256, 0, stream>>>(X0hi, X0lo, sq, Abf, degp, Fp, bsh, BCv);
            disscale_kernel<<<16 * BCv, 256, 0, stream>>>(X0t, degp, dis, Fp, bsh, BCv);
            lx_kernel<<<ft * 16 * BCv, 256, 0, stream>>>(
                Abf, dis, X0t, nullptr, X1t, X1b, F, Fp, 0, ft, bsh);
            lx_kernel<<<ft * 16 * BCv, 256, 0, stream>>>(
                Abf, dis, X1t, X0t, nullptr, X2b, F, Fp, 1, ft, bsh);
            proj_kernel<<<n_g * 8 * BCv, 256, 0, stream>>>(
                X0hi, X1b, X2b, Ld.Wtl, Ld.bias, Ld.O, pool, Fp, Ld.Fo, b0, n_g, bsh);
        }
    }

    fc_kernel<<<dim3(8, 32), 256, 0, stream>>>(pool, fc1w, fc1b, f1, 1024, 512, 1);
    fc_kernel<<<dim3(2, 32), 256, 0, stream>>>(f1, fc2w, fc2b, f2, 512, 128, 1);
    fc_kernel<<<dim3(1, 32), 256, 0, stream>>>(f2, fc3w, fc3b, out, 128, 40, 0);
}